// Round 9
// baseline (59.818 us; speedup 1.0000x reference)
//
#include <hip/hip_runtime.h>
#include <hip/hip_bf16.h>
#include <math.h>

#define D_SINGLE 512
#define D_PAIR   128
#define RANK     32
#define NROW     512
#define EPS      1e-5f

typedef __attribute__((ext_vector_type(8))) short bf16x8;  // 8 bf16 = 4 VGPRs
typedef __attribute__((ext_vector_type(4))) float f32x4;

__device__ __forceinline__ float dot4(f32x4 a, f32x4 b) {
    return a.x * b.x + a.y * b.y + a.z * b.z + a.w * b.w;
}

// ---------------------------------------------------------------------------
// Fused kernel 1+2 (block-specialized, one dispatch so a-side and b-side run
// concurrently instead of as two serialized tiny launches).
//  blocks 0..511   : a-side. One row each, 512 thr. LN (1 elem/thr) + 32-wide
//                    projection (wave w does r = w*4+q), write a_bf (bf16).
//  blocks 512..639 : b-side. Pair (g = bb>>1, seg = bb&1) per 8-row j-group.
//                    B1: wave w LNs row jw = 8g+w -> xnb[w][512] in LDS.
//                    B2: in-wave proj: r = lane&31, half = lane>>5, f32x4
//                        dots + shfl_xor(32) -> bl[w*32+r] in LDS.
//                    B3: k2 contraction for pr = (seg*4+it)*512 + t:
//                        wb[j][p*32+r] = sum_s bl[j][s] * w_out[p][r*32+s].
//                    (seg halves the pr range so B3 wall time halves; B1/B2
//                    are recomputed identically in both blocks of a pair.)
// ---------------------------------------------------------------------------
__global__ __launch_bounds__(512) void k12_fused(
    const float* __restrict__ xa, const float* __restrict__ xb,
    const float* __restrict__ ln_g, const float* __restrict__ ln_b,
    const float* __restrict__ wl, const float* __restrict__ bL,
    const float* __restrict__ wr, const float* __restrict__ bR,
    const float* __restrict__ w_out,
    __hip_bfloat16* __restrict__ a_bf, __hip_bfloat16* __restrict__ wb)
{
    const int bid  = blockIdx.x;
    const int t    = threadIdx.x;
    const int wv   = t >> 6;
    const int lane = t & 63;

    if (bid < NROW) {
        // ---------------- a-side: one row, 512 threads ----------------
        __shared__ float xn[D_SINGLE];
        __shared__ float red[16];
        const float* x = xa + bid * D_SINGLE;

        float x0 = x[t];
        float s = x0, ss = x0 * x0;
        #pragma unroll
        for (int m = 1; m < 64; m <<= 1) {
            s  += __shfl_xor(s, m);
            ss += __shfl_xor(ss, m);
        }
        if (lane == 0) { red[wv] = s; red[8 + wv] = ss; }
        __syncthreads();
        float S = 0.f, SS = 0.f;
        #pragma unroll
        for (int w = 0; w < 8; ++w) { S += red[w]; SS += red[8 + w]; }
        const float mean = S * (1.0f / D_SINGLE);
        const float var  = SS * (1.0f / D_SINGLE) - mean * mean;
        const float rstd = rsqrtf(var + EPS);
        xn[t] = (x0 - mean) * rstd * ln_g[t] + ln_b[t];
        __syncthreads();

        #pragma unroll
        for (int q = 0; q < 4; ++q) {
            const int r = wv * 4 + q;
            float acc = 0.f;
            #pragma unroll
            for (int tt = 0; tt < 8; ++tt) {
                const int k = lane + 64 * tt;
                acc += xn[k] * wl[r * D_SINGLE + k];
            }
            #pragma unroll
            for (int m = 1; m < 64; m <<= 1) acc += __shfl_xor(acc, m);
            if (lane == 0)
                a_bf[bid * RANK + r] = __float2bfloat16(acc + bL[r]);
        }
    } else {
        // ---------------- b-side: 8 rows + wb contraction ----------------
        const int bb  = bid - NROW;     // 0..127
        const int g   = bb >> 1;        // j-group 0..63
        const int seg = bb & 1;         // pr-range half

        __shared__ __align__(16) float xnb[8][D_SINGLE];  // 16 KB
        __shared__ __align__(16) float bl[8 * RANK];      // 1 KB

        // B1: LN of row jw = 8g + wv (one row per wave)
        const int jw = g * 8 + wv;
        const float* x = xb + jw * D_SINGLE;
        float v[8];
        float s = 0.f, ss = 0.f;
        #pragma unroll
        for (int k = 0; k < 8; ++k) {
            v[k] = x[lane + 64 * k];
            s += v[k]; ss += v[k] * v[k];
        }
        #pragma unroll
        for (int m = 1; m < 64; m <<= 1) {
            s  += __shfl_xor(s, m);
            ss += __shfl_xor(ss, m);
        }
        const float mean = s * (1.0f / D_SINGLE);
        const float var  = ss * (1.0f / D_SINGLE) - mean * mean;
        const float rstd = rsqrtf(var + EPS);
        #pragma unroll
        for (int k = 0; k < 8; ++k) {
            const int e = lane + 64 * k;
            xnb[wv][e] = (v[k] - mean) * rstd * ln_g[e] + ln_b[e];
        }
        __syncthreads();

        // B2: projection, in-wave: r = lane&31, half = lane>>5
        const int r    = lane & 31;
        const int half = lane >> 5;
        const f32x4* wr4 = reinterpret_cast<const f32x4*>(wr + r * D_SINGLE + half * 256);
        const f32x4* xv4 = reinterpret_cast<const f32x4*>(&xnb[wv][half * 256]);
        float acc = 0.f;
        #pragma unroll
        for (int k4 = 0; k4 < 64; ++k4)
            acc += dot4(wr4[k4], xv4[k4]);
        acc += __shfl_xor(acc, 32);
        if (half == 0) bl[wv * 32 + r] = acc + bR[r];
        __syncthreads();

        // B3: wb contraction for this block's pr half-range
        const f32x4* bl4 = reinterpret_cast<const f32x4*>(bl);
        #pragma unroll
        for (int it = 0; it < 4; ++it) {
            const int pr = (seg * 4 + it) * 512 + t;
            const int p  = pr >> 5;
            const int rr = pr & 31;
            const f32x4* wrow = reinterpret_cast<const f32x4*>(w_out + p * (RANK * RANK) + rr * RANK);
            f32x4 w8[8];
            #pragma unroll
            for (int q = 0; q < 8; ++q) w8[q] = wrow[q];
            #pragma unroll
            for (int jj = 0; jj < 8; ++jj) {
                float a2 = 0.f;
                #pragma unroll
                for (int q = 0; q < 8; ++q) a2 += dot4(w8[q], bl4[jj * 8 + q]);
                wb[(size_t)(g * 8 + jj) * 4096 + pr] = __float2bfloat16(a2);
            }
        }
    }
}

// ---------------------------------------------------------------------------
// Kernel 3 (unchanged from round 8: MFMA + LDS-staged + nontemporal stores).
// C/D map: p = tt*16 + g*4 + r, i = i0 + c (m89-verified, passed r4-r8).
// ---------------------------------------------------------------------------
__global__ __launch_bounds__(256, 4) void k3_mfma(
    const __hip_bfloat16* __restrict__ a_bf, const __hip_bfloat16* __restrict__ wb_bf,
    const float* __restrict__ b_out, const float* __restrict__ lno_g,
    const float* __restrict__ lno_b, float* __restrict__ out)
{
    const int t    = threadIdx.x;
    const int wv   = t >> 6;          // 0..3 -> j within quad
    const int lane = t & 63;
    const int g    = lane >> 4;
    const int c    = lane & 15;
    const int jt   = blockIdx.x & 127;   // fast dim -> XCD j-locality
    const int ib   = blockIdx.x >> 7;    // 0..31
    const int j0   = jt * 4;
    const int i0   = ib * 16;
    const int j    = j0 + wv;

    __shared__ __align__(16) float L[16 * 4 * D_PAIR];   // 32 KB

    const short* a_s = reinterpret_cast<const short*>(a_bf);
    const short* wbj = reinterpret_cast<const short*>(wb_bf) + (size_t)j * 4096;

    // ---- Phase 1: MFMA + LN (all operand loads transient) ----
    bf16x8 bfrag = *reinterpret_cast<const bf16x8*>(a_s + (i0 + c) * RANK + g * 8);

    f32x4 acc[8];
    #pragma unroll
    for (int tt = 0; tt < 8; ++tt) {
        bf16x8 af  = *reinterpret_cast<const bf16x8*>(wbj + (tt * 16 + c) * RANK + g * 8);
        f32x4  cin = *reinterpret_cast<const f32x4*>(b_out + tt * 16 + g * 4);
        acc[tt] = __builtin_amdgcn_mfma_f32_16x16x32_bf16(af, bfrag, cin, 0, 0, 0);
    }

    float s = 0.f, ss = 0.f;
    #pragma unroll
    for (int tt = 0; tt < 8; ++tt) {
        #pragma unroll
        for (int r = 0; r < 4; ++r) { float v = acc[tt][r]; s += v; ss += v * v; }
    }
    s  += __shfl_xor(s, 16);  ss += __shfl_xor(ss, 16);
    s  += __shfl_xor(s, 32);  ss += __shfl_xor(ss, 32);
    const float mean = s * (1.0f / D_PAIR);
    const float var  = ss * (1.0f / D_PAIR) - mean * mean;
    const float rstd = rsqrtf(var + EPS);

    // normalized tile -> LDS, slot-swizzled (bits 4..6 ^= i&7)
    #pragma unroll
    for (int tt = 0; tt < 8; ++tt) {
        f32x4 gm = *reinterpret_cast<const f32x4*>(lno_g + tt * 16 + g * 4);
        f32x4 bt = *reinterpret_cast<const f32x4*>(lno_b + tt * 16 + g * 4);
        f32x4 o;
        #pragma unroll
        for (int r = 0; r < 4; ++r)
            o[r] = (acc[tt][r] - mean) * rstd * gm[r] + bt[r];
        int off = c * 2048 + wv * 512 + tt * 64 + g * 16;   // bytes
        off ^= (c & 7) << 4;
        *reinterpret_cast<f32x4*>(reinterpret_cast<char*>(L) + off) = o;
    }
    __syncthreads();

    // ---- Phase 2: coalesced nontemporal sweep store ----
    const int f     = t & 127;        // 128 threads cover one i-row (2 KB)
    const int ihalf = t >> 7;         // 2 rows per round
    #pragma unroll
    for (int rnd = 0; rnd < 8; ++rnd) {
        const int i = rnd * 2 + ihalf;
        int off = i * 2048 + f * 16;
        off ^= (i & 7) << 4;
        f32x4 v = *reinterpret_cast<const f32x4*>(reinterpret_cast<const char*>(L) + off);
        float* dst = out + (size_t)(i0 + i) * (NROW * D_PAIR) + j0 * D_PAIR + f * 4;
        __builtin_nontemporal_store(v, reinterpret_cast<f32x4*>(dst));
    }
}

// ---------------------------------------------------------------------------
extern "C" void kernel_launch(void* const* d_in, const int* in_sizes, int n_in,
                              void* d_out, int out_size, void* d_ws, size_t ws_size,
                              hipStream_t stream) {
    const float* single_a = (const float*)d_in[0];
    const float* single_b = (const float*)d_in[1];
    const float* ln_g     = (const float*)d_in[2];
    const float* ln_b     = (const float*)d_in[3];
    const float* w_left   = (const float*)d_in[4];
    const float* b_left   = (const float*)d_in[5];
    const float* w_right  = (const float*)d_in[6];
    const float* b_right  = (const float*)d_in[7];
    const float* w_out    = (const float*)d_in[8];
    const float* b_out    = (const float*)d_in[9];
    const float* lno_g    = (const float*)d_in[10];
    const float* lno_b    = (const float*)d_in[11];
    float* out = (float*)d_out;

    float* ws = (float*)d_ws;
    __hip_bfloat16* a_bf  = (__hip_bfloat16*)ws;                     // 512*32 bf16 = 32 KB
    __hip_bfloat16* wb_bf = (__hip_bfloat16*)(ws + 32768);           // 512*4096 bf16 = 4 MB

    k12_fused<<<NROW + 128, 512, 0, stream>>>(single_a, single_b, ln_g, ln_b,
                                              w_left, b_left, w_right, b_right,
                                              w_out, a_bf, wb_bf);
    k3_mfma<<<4096, 256, 0, stream>>>(a_bf, wb_bf, b_out, lno_g, lno_b, out);
}